// Round 1
// baseline (153.697 us; speedup 1.0000x reference)
//
#include <hip/hip_runtime.h>
#include <hip/hip_bf16.h>

typedef unsigned int u32;
typedef unsigned short u16;

#define N_BATCH 8192
#define EMB_DIM 128
#define MARGIN 1.0f
#define PAIR_CAP_MAX (1u << 20)   // 1M pairs * 8B = 8MB; expected ~524K
#define PBUF_CAP 4096             // per-block LDS pair staging entries

typedef __attribute__((ext_vector_type(8))) short bf16x8;   // 8 bf16 = 4 VGPRs
typedef __attribute__((ext_vector_type(4))) float f32x4;    // MFMA 16x16 acc

// ---------------------------------------------------------------------------
// Kernel 1: bf16 cast + row sq-norms + init neg_min / totals
// ---------------------------------------------------------------------------
__global__ __launch_bounds__(128) void k_prep(const float* __restrict__ emb,
                                              u16* __restrict__ ebf,
                                              float* __restrict__ sq,
                                              u32* __restrict__ negmin,
                                              u32* __restrict__ totals) {
    int row = blockIdx.x;
    int t = threadIdx.x;
    float x = emb[row * EMB_DIM + t];
    // RNE fp32 -> bf16
    u32 u = __float_as_uint(x);
    u16 b = (u16)((u + 0x7fffu + ((u >> 16) & 1u)) >> 16);
    ebf[row * EMB_DIM + t] = b;

    float v = x * x;
#pragma unroll
    for (int off = 32; off > 0; off >>= 1) v += __shfl_down(v, off, 64);
    __shared__ float wsum[2];
    if ((t & 63) == 0) wsum[t >> 6] = v;
    __syncthreads();
    if (t == 0) {
        sq[row] = wsum[0] + wsum[1];
        negmin[row] = 0x7f7fffffu;  // FLT_MAX bits (all dists >= 0 -> uint order == float order)
        if (row == 0) { totals[0] = 0u; totals[1] = 0u; totals[2] = 0u; }
    }
}

// ---------------------------------------------------------------------------
// Kernel 2: fused Gram + masked row/col min + same-class pair compaction.
// Tile 128x128, bf16 MFMA 16x16x32, K=128 single staging, symmetric (by>=bx).
// ---------------------------------------------------------------------------
__global__ __launch_bounds__(256) void k_gram(const u16* __restrict__ ebf,
                                              const float* __restrict__ sq,
                                              const int* __restrict__ labels,
                                              u32* __restrict__ negmin,
                                              u32* __restrict__ totals,     // [2] = global pair count
                                              uint2* __restrict__ pairs,
                                              u32 pairCap) {
    const int bx = blockIdx.x, by = blockIdx.y;
    if (by < bx) return;                 // symmetry: process upper-triangular tiles only
    const int R = bx * 128, C = by * 128;
    const bool diag = (bx == by);

    __shared__ uint4 smem[4096];         // 64 KB: A tile (32K) + B tile (32K); reused for epilogue
    uint4* As = smem;                    // [128 rows][16 chunks of 8 bf16], XOR-swizzled
    uint4* Bs = smem + 2048;

    const int t = threadIdx.x;
    const int lane = t & 63, w = t >> 6;
    const uint4* gE = (const uint4*)ebf; // row r -> gE[r*16 + chunk]

    // ---- stage A (rows R..R+127) and B (rows C..C+127), 16B/lane coalesced, XOR swizzle
#pragma unroll
    for (int it = 0; it < 8; ++it) {
        int g = t + it * 256;            // 0..2047
        int row = g >> 4, ch = g & 15;
        As[row * 16 + (ch ^ (row & 15))] = gE[(R + row) * 16 + ch];
    }
#pragma unroll
    for (int it = 0; it < 8; ++it) {
        int g = t + it * 256;
        int row = g >> 4, ch = g & 15;
        Bs[row * 16 + (ch ^ (row & 15))] = gE[(C + row) * 16 + ch];
    }
    __syncthreads();

    // ---- MFMA: wave w computes rows [w*32, w*32+32) x all 128 cols
    const int c16 = lane & 15, quad = lane >> 4;
    const int mb = w * 32;
    f32x4 acc[2][8];
#pragma unroll
    for (int i = 0; i < 2; ++i)
#pragma unroll
        for (int j = 0; j < 8; ++j) acc[i][j] = (f32x4){0.f, 0.f, 0.f, 0.f};

    const bf16x8* As8 = (const bf16x8*)As;
    const bf16x8* Bs8 = (const bf16x8*)Bs;

#pragma unroll
    for (int kc = 0; kc < 4; ++kc) {     // K = 4 chunks of 32
        // A frag: lane holds A[m=lane&15][k=quad*8 .. +7]
        int ar0 = mb + c16;
        bf16x8 a0 = As8[ar0 * 16 + ((kc * 4 + quad) ^ (ar0 & 15))];
        int ar1 = mb + 16 + c16;
        bf16x8 a1 = As8[ar1 * 16 + ((kc * 4 + quad) ^ (ar1 & 15))];
        bf16x8 b[8];
#pragma unroll
        for (int j = 0; j < 8; ++j) {
            int br = j * 16 + c16;
            b[j] = Bs8[br * 16 + ((kc * 4 + quad) ^ (br & 15))];
        }
#pragma unroll
        for (int j = 0; j < 8; ++j) {
            acc[0][j] = __builtin_amdgcn_mfma_f32_16x16x32_bf16(a0, b[j], acc[0][j], 0, 0, 0);
            acc[1][j] = __builtin_amdgcn_mfma_f32_16x16x32_bf16(a1, b[j], acc[1][j], 0, 0, 0);
        }
    }
    __syncthreads();                     // tile reads done; reuse smem for epilogue

    // ---- smem reuse: rowmin[128] | colmin[128] | paircnt | pairbase | pad | pbuf[PBUF_CAP]
    u32* smem32 = (u32*)smem;
    u32* rowmin = smem32;
    u32* colmin = smem32 + 128;
    u32* paircnt = smem32 + 256;
    u32* pairbase = smem32 + 257;
    uint2* pbuf = (uint2*)(smem32 + 260); // byte offset 1040, 8B aligned

    smem32[t] = 0x7f7fffffu;             // t<256 inits rowmin+colmin
    if (t == 0) *paircnt = 0u;
    __syncthreads();

    // ---- preload per-lane row/col metadata from global (L1/L2 resident, 32KB arrays)
    float rs[8]; int rl[8];
#pragma unroll
    for (int i = 0; i < 2; ++i)
#pragma unroll
        for (int rg = 0; rg < 4; ++rg) {
            int grow = R + mb + i * 16 + quad * 4 + rg;
            rs[i * 4 + rg] = sq[grow];
            rl[i * 4 + rg] = labels[grow];
        }
    float cs[8]; int cl[8];
#pragma unroll
    for (int j = 0; j < 8; ++j) {
        int gcol = C + j * 16 + c16;
        cs[j] = sq[gcol];
        cl[j] = labels[gcol];
    }

    // ---- epilogue: dist, masked min (rows and cols), pair compaction
    float cm[8];
#pragma unroll
    for (int j = 0; j < 8; ++j) cm[j] = 3.3e38f;

#pragma unroll
    for (int i = 0; i < 2; ++i) {
        float rm[4] = {3.3e38f, 3.3e38f, 3.3e38f, 3.3e38f};
#pragma unroll
        for (int j = 0; j < 8; ++j) {
#pragma unroll
            for (int rg = 0; rg < 4; ++rg) {
                // C/D layout (m89/m91-verified): D[row=quad*4+reg][col=lane&15]
                float g = acc[i][j][rg];
                float d = fmaf(-2.f, g, rs[i * 4 + rg] + cs[j]);
                bool same = (rl[i * 4 + rg] == cl[j]);
                float cand = same ? 3.3e38f : fmaxf(d, 0.f);
                rm[rg] = fminf(rm[rg], cand);
                cm[j] = fminf(cm[j], cand);
                int grow = R + mb + i * 16 + quad * 4 + rg;
                int gcol = C + j * 16 + c16;
                if (same && grow < gcol) {   // upper-triangle same-class pair -> record
                    u32 idx = atomicAdd(paircnt, 1u);
                    if (idx < PBUF_CAP) {
                        pbuf[idx] = make_uint2(__float_as_uint(d), (u32)grow);
                    } else {                 // overflow: spill directly (rare)
                        u32 gi = atomicAdd(&totals[2], 1u);
                        if (gi < pairCap) pairs[gi] = make_uint2(__float_as_uint(d), (u32)grow);
                    }
                }
            }
        }
        // row-min: reduce across the 16 lanes of each quad (cols), then LDS atomic
#pragma unroll
        for (int rg = 0; rg < 4; ++rg) {
            float v = rm[rg];
            v = fminf(v, __shfl_xor(v, 1, 64));
            v = fminf(v, __shfl_xor(v, 2, 64));
            v = fminf(v, __shfl_xor(v, 4, 64));
            v = fminf(v, __shfl_xor(v, 8, 64));
            if (c16 == 0) atomicMin(&rowmin[mb + i * 16 + quad * 4 + rg], __float_as_uint(v));
        }
    }
    if (!diag) {
        // col-min: reduce across quads (rows), symmetric contribution d(c,r)=d(r,c)
#pragma unroll
        for (int j = 0; j < 8; ++j) {
            float v = cm[j];
            v = fminf(v, __shfl_xor(v, 16, 64));
            v = fminf(v, __shfl_xor(v, 32, 64));
            if (quad == 0) atomicMin(&colmin[j * 16 + c16], __float_as_uint(v));
        }
    }
    __syncthreads();

    // ---- one global atomicMin per row/col; reserve pair range
    if (t < 128) atomicMin(&negmin[R + t], rowmin[t]);
    else if (!diag) atomicMin(&negmin[C + t - 128], colmin[t - 128]);
    if (t == 0) {
        u32 cnt = *paircnt; if (cnt > PBUF_CAP) cnt = PBUF_CAP;
        *pairbase = atomicAdd(&totals[2], cnt);
    }
    __syncthreads();

    // ---- coalesced pair flush
    {
        u32 cnt = *paircnt; if (cnt > PBUF_CAP) cnt = PBUF_CAP;
        u32 base = *pairbase;
        for (u32 k = t; k < cnt; k += 256)
            if (base + k < pairCap) pairs[base + k] = pbuf[k];
    }
}

// ---------------------------------------------------------------------------
// Kernel 3: val = d - neg_min[anchor] + margin; accumulate sum & count
// ---------------------------------------------------------------------------
__global__ __launch_bounds__(256) void k_pairs(const uint2* __restrict__ pairs,
                                               const u32* __restrict__ negmin,
                                               const u32* __restrict__ totalsU,
                                               float* __restrict__ totalsF,
                                               u32 pairCap) {
    u32 n = totalsU[2]; if (n > pairCap) n = pairCap;
    float s = 0.f, c = 0.f;
    for (u32 k = blockIdx.x * 256u + threadIdx.x; k < n; k += gridDim.x * 256u) {
        uint2 p = pairs[k];
        float val = __uint_as_float(p.x) + MARGIN - __uint_as_float(negmin[p.y]);
        if (val > 0.f) { s += val; c += 1.f; }
    }
#pragma unroll
    for (int off = 32; off > 0; off >>= 1) {
        s += __shfl_down(s, off, 64);
        c += __shfl_down(c, off, 64);
    }
    __shared__ float bs[4], bc[4];
    int lane = threadIdx.x & 63, w = threadIdx.x >> 6;
    if (lane == 0) { bs[w] = s; bc[w] = c; }
    __syncthreads();
    if (threadIdx.x == 0) {
        float S = bs[0] + bs[1] + bs[2] + bs[3];
        float Cc = bc[0] + bc[1] + bc[2] + bc[3];
        if (S != 0.f || Cc != 0.f) {
            atomicAdd(&totalsF[0], S);
            atomicAdd(&totalsF[1], Cc);
        }
    }
}

// ---------------------------------------------------------------------------
// Kernel 4: final scalar
// ---------------------------------------------------------------------------
__global__ void k_final(const float* __restrict__ totals, float* __restrict__ out) {
    out[0] = totals[0] / fmaxf(totals[1], 1.0f);
}

// ---------------------------------------------------------------------------
extern "C" void kernel_launch(void* const* d_in, const int* in_sizes, int n_in,
                              void* d_out, int out_size, void* d_ws, size_t ws_size,
                              hipStream_t stream) {
    const float* emb = (const float*)d_in[0];
    const int* labels = (const int*)d_in[1];

    // workspace carving
    char* w = (char*)d_ws;
    const size_t ebf_bytes = (size_t)N_BATCH * EMB_DIM * sizeof(u16);  // 2 MB
    u16* ebf = (u16*)w;
    float* sq = (float*)(w + ebf_bytes);                               // 32 KB
    u32* negmin = (u32*)(w + ebf_bytes + N_BATCH * 4);                 // 32 KB
    u32* totals = (u32*)(w + ebf_bytes + 2 * (size_t)N_BATCH * 4);     // 256 B slot
    const size_t fixed = ebf_bytes + 2 * (size_t)N_BATCH * 4 + 256;
    uint2* pairs = (uint2*)(w + fixed);
    u32 pairCap = PAIR_CAP_MAX;
    if (ws_size > fixed) {
        size_t avail = (ws_size - fixed) / sizeof(uint2);
        if (avail < pairCap) pairCap = (u32)avail;
    } else {
        pairCap = 0;
    }

    k_prep<<<N_BATCH, 128, 0, stream>>>(emb, ebf, sq, negmin, totals);
    dim3 grid(64, 64);
    k_gram<<<grid, 256, 0, stream>>>(ebf, sq, labels, negmin, totals, pairs, pairCap);
    k_pairs<<<512, 256, 0, stream>>>(pairs, negmin, totals, (float*)totals, pairCap);
    k_final<<<1, 1, 0, stream>>>((const float*)totals, (float*)d_out);
}

// Round 2
// 152.482 us; speedup vs baseline: 1.0080x; 1.0080x over previous
//
#include <hip/hip_runtime.h>
#include <hip/hip_bf16.h>

typedef unsigned int u32;
typedef unsigned short u16;
typedef unsigned long long u64;

#define N_BATCH 8192
#define EMB_DIM 128
#define MARGIN 1.0f
#define PAIR_CAP_MAX (640u * 1024u)   // 5 MB; expected ~524K pairs
#define PBUF_CAP 3840                 // LDS pair staging entries (fits in 32KB with headers)
#define BIGF 3.3e38f

typedef __attribute__((ext_vector_type(8))) short bf16x8;   // 8 bf16 = 4 VGPRs
typedef __attribute__((ext_vector_type(4))) float f32x4;    // MFMA 16x16 acc

// async global->LDS, 16B per lane; lds dest must be wave-uniform base (+lane*16 implicit)
__device__ inline void async_ld16(const void* g, void* l) {
    __builtin_amdgcn_global_load_lds(
        (const __attribute__((address_space(1))) unsigned int*)g,
        (__attribute__((address_space(3))) unsigned int*)l, 16, 0, 0);
}

// ---------------------------------------------------------------------------
// Kernel 1: bf16 cast + row sq-norms + zero totals. 1024 blocks x 256 thr,
// 8 rows/block, 32 lanes/row, float4 loads.
// ---------------------------------------------------------------------------
__global__ __launch_bounds__(256) void k_prep(const float* __restrict__ emb,
                                              u16* __restrict__ ebf,
                                              float* __restrict__ sq,
                                              u32* __restrict__ totals) {
    int t = threadIdx.x;
    int r = blockIdx.x * 8 + (t >> 5);
    int l32 = t & 31;
    float4 x = ((const float4*)emb)[(size_t)r * 32 + l32];
    u32 ux = __float_as_uint(x.x), uy = __float_as_uint(x.y);
    u32 uz = __float_as_uint(x.z), uw = __float_as_uint(x.w);
    ushort4 b;
    b.x = (u16)((ux + 0x7fffu + ((ux >> 16) & 1u)) >> 16);
    b.y = (u16)((uy + 0x7fffu + ((uy >> 16) & 1u)) >> 16);
    b.z = (u16)((uz + 0x7fffu + ((uz >> 16) & 1u)) >> 16);
    b.w = (u16)((uw + 0x7fffu + ((uw >> 16) & 1u)) >> 16);
    ((ushort4*)ebf)[(size_t)r * 32 + l32] = b;

    float v = fmaf(x.x, x.x, fmaf(x.y, x.y, fmaf(x.z, x.z, x.w * x.w)));
    v += __shfl_down(v, 16, 64);   // 32-lane reduce; lanes 0 and 32 hold row sums
    v += __shfl_down(v, 8, 64);
    v += __shfl_down(v, 4, 64);
    v += __shfl_down(v, 2, 64);
    v += __shfl_down(v, 1, 64);
    if (l32 == 0) sq[r] = v;
    if (blockIdx.x == 0 && t < 3) totals[t] = 0u;   // sumF, cntF, pairCnt
}

// ---------------------------------------------------------------------------
// Kernel 2: fused Gram + masked row/col min (-> partial matrix, atomic-free)
// + same-class pair compaction. Triangular 1D grid (2080 blocks), 128x128
// tile, B in 32KB LDS via global_load_lds (XOR-swizzled at the source),
// A frags straight from global. Each wave: 64 rows x 64 cols.
// ---------------------------------------------------------------------------
__global__ __launch_bounds__(256, 4) void k_gram(const u16* __restrict__ ebf,
                                                 const float* __restrict__ sq,
                                                 const int* __restrict__ labels,
                                                 u32* __restrict__ partial,   // [64][8192]
                                                 u32* __restrict__ gPairCnt,  // &totals[2]
                                                 uint2* __restrict__ pairs,
                                                 u32 pairCap) {
    // ---- triangular decode: idx -> (bx, by), by >= bx
    int idx = blockIdx.x;
    float ff = (129.0f - sqrtf(16641.0f - 8.0f * (float)idx)) * 0.5f;
    int bx = (int)ff;
    if (bx > 63) bx = 63;
    while (bx > 0 && idx < bx * 64 - (bx * (bx - 1)) / 2) --bx;
    while (idx >= (bx + 1) * 64 - ((bx + 1) * bx) / 2) ++bx;
    int by = bx + idx - (bx * 64 - (bx * (bx - 1)) / 2);
    const int R = bx * 128, C = by * 128;
    const bool diag = (bx == by);

    __shared__ uint4 Bs[2048];   // 32 KB: B tile, XOR-swizzled; reused for epilogue
    const int t = threadIdx.x;
    const int lane = t & 63, w = t >> 6;
    const int c16 = lane & 15, quad = lane >> 4;
    const uint4* gE = (const uint4*)ebf;   // row r -> gE[r*16 + chunk]

    // ---- stage B tile (rows C..C+127) via async DMA, swizzle folded into source addr
#pragma unroll
    for (int it = 0; it < 8; ++it) {
        int s = w * 512 + it * 64 + lane;          // LDS uint4 slot
        int row = s >> 4, chPos = s & 15;
        int ch = chPos ^ (row & 15);               // involutive XOR swizzle
        async_ld16(gE + (size_t)(C + row) * 16 + ch, Bs + (w * 512 + it * 64));
    }

    // ---- wave partition: 2x2, each wave 64 rows x 64 cols
    const int mb = (w & 1) * 64;
    const int nb = (w >> 1) * 64;
    f32x4 acc[4][4];
#pragma unroll
    for (int i = 0; i < 4; ++i)
#pragma unroll
        for (int j = 0; j < 4; ++j) acc[i][j] = (f32x4){0.f, 0.f, 0.f, 0.f};

    const bf16x8* gA8 = (const bf16x8*)ebf;
    // prefetch kc=0 A frags before the barrier (independent of LDS DMA)
    bf16x8 a[4];
#pragma unroll
    for (int i = 0; i < 4; ++i)
        a[i] = gA8[(size_t)(R + mb + i * 16 + c16) * 16 + quad];

    __syncthreads();   // drains the LDS-DMA (vmcnt(0) before s_barrier)

    const bf16x8* Bs8 = (const bf16x8*)Bs;
#pragma unroll
    for (int kc = 0; kc < 4; ++kc) {
        int kch = kc * 4 + quad;
        bf16x8 b[4];
#pragma unroll
        for (int j = 0; j < 4; ++j) {
            int br = nb + j * 16 + c16;
            b[j] = Bs8[br * 16 + (kch ^ (br & 15))];
        }
        bf16x8 an[4];
        if (kc < 3) {
            int kn = (kc + 1) * 4 + quad;
#pragma unroll
            for (int i = 0; i < 4; ++i)
                an[i] = gA8[(size_t)(R + mb + i * 16 + c16) * 16 + kn];
        }
#pragma unroll
        for (int i = 0; i < 4; ++i)
#pragma unroll
            for (int j = 0; j < 4; ++j)
                acc[i][j] = __builtin_amdgcn_mfma_f32_16x16x32_bf16(a[i], b[j], acc[i][j], 0, 0, 0);
        if (kc < 3) {
#pragma unroll
            for (int i = 0; i < 4; ++i) a[i] = an[i];
        }
    }
    __syncthreads();   // B reads done; reuse LDS for epilogue

    // ---- LDS reuse: rowmin[128] | colmin[128] | paircnt | pairbase | pbuf
    u32* smem32 = (u32*)Bs;
    u32* rowmin = smem32;
    u32* colmin = smem32 + 128;
    u32* paircnt = smem32 + 256;
    u32* pairbase = smem32 + 257;
    uint2* pbuf = (uint2*)(smem32 + 260);   // byte 1040, 8B aligned

    smem32[t] = 0x7f7fffffu;   // t<256 inits rowmin+colmin
    if (t == 0) *paircnt = 0u;
    __syncthreads();

    // per-lane column metadata (4 cols)
    float cs_[4]; int cl_[4];
#pragma unroll
    for (int j = 0; j < 4; ++j) {
        int gc = C + nb + j * 16 + c16;
        cs_[j] = sq[gc];
        cl_[j] = labels[gc];
    }
    float cm[4] = {BIGF, BIGF, BIGF, BIGF};

#pragma unroll
    for (int i = 0; i < 4; ++i) {
        const int rowbase = mb + i * 16 + quad * 4;
        float rs_[4]; int rl_[4];
#pragma unroll
        for (int rg = 0; rg < 4; ++rg) {
            int gr = R + rowbase + rg;
            rs_[rg] = sq[gr];
            rl_[rg] = labels[gr];
        }
        float rm[4] = {BIGF, BIGF, BIGF, BIGF};
#pragma unroll
        for (int j = 0; j < 4; ++j) {
#pragma unroll
            for (int rg = 0; rg < 4; ++rg) {
                // C/D layout (m89/m91-verified): D[row=quad*4+reg][col=lane&15]
                float d = fmaf(-2.f, acc[i][j][rg], rs_[rg] + cs_[j]);
                bool same = (rl_[rg] == cl_[j]);
                float cand = same ? BIGF : fmaxf(d, 0.f);
                rm[rg] = fminf(rm[rg], cand);
                cm[j] = fminf(cm[j], cand);
                int grow = R + rowbase + rg;
                int gcol = C + nb + j * 16 + c16;
                bool take = same && (grow < gcol);
                u64 mask = __ballot(take);
                if (mask) {   // wave-aggregated pair push: 1 LDS atomic per wave
                    int leader = __ffsll((long long)mask) - 1;
                    u32 base = 0;
                    if (lane == leader) base = atomicAdd(paircnt, (u32)__popcll(mask));
                    base = __shfl(base, leader, 64);
                    if (take) {
                        u32 pidx = base + (u32)__popcll(mask & ((1ull << lane) - 1u));
                        if (pidx < PBUF_CAP) {
                            pbuf[pidx] = make_uint2(__float_as_uint(d), (u32)grow);
                        } else {   // overflow spill (rare)
                            u32 gi = atomicAdd(gPairCnt, 1u);
                            if (gi < pairCap) pairs[gi] = make_uint2(__float_as_uint(d), (u32)grow);
                        }
                    }
                }
            }
        }
        // row-min: reduce across the 16 col-lanes, then LDS atomic
#pragma unroll
        for (int rg = 0; rg < 4; ++rg) {
            float v = rm[rg];
            v = fminf(v, __shfl_xor(v, 1, 64));
            v = fminf(v, __shfl_xor(v, 2, 64));
            v = fminf(v, __shfl_xor(v, 4, 64));
            v = fminf(v, __shfl_xor(v, 8, 64));
            if (c16 == 0) atomicMin(&rowmin[rowbase + rg], __float_as_uint(v));
        }
    }
    if (!diag) {
        // col-min: reduce across quads (symmetric contribution d(c,r)=d(r,c))
#pragma unroll
        for (int j = 0; j < 4; ++j) {
            float v = cm[j];
            v = fminf(v, __shfl_xor(v, 16, 64));
            v = fminf(v, __shfl_xor(v, 32, 64));
            if (quad == 0) atomicMin(&colmin[nb + j * 16 + c16], __float_as_uint(v));
        }
    }
    __syncthreads();

    // ---- atomic-free negmin partials: each slot written exactly once, coalesced
    if (t < 128) partial[(size_t)by * N_BATCH + R + t] = rowmin[t];
    else if (!diag) partial[(size_t)bx * N_BATCH + C + (t - 128)] = colmin[t - 128];
    if (t == 0) {
        u32 c = *paircnt; if (c > PBUF_CAP) c = PBUF_CAP;
        *pairbase = atomicAdd(gPairCnt, c);
    }
    __syncthreads();

    // ---- coalesced pair flush
    {
        u32 cnt = *paircnt; if (cnt > PBUF_CAP) cnt = PBUF_CAP;
        u32 base = *pairbase;
        for (u32 k = t; k < cnt; k += 256)
            if (base + k < pairCap) pairs[base + k] = pbuf[k];
    }
}

// ---------------------------------------------------------------------------
// Kernel 3: negmin[r] = min over 64 partials (both sides coalesced)
// ---------------------------------------------------------------------------
__global__ __launch_bounds__(256) void k_negmin(const u32* __restrict__ partial,
                                                float* __restrict__ negmin) {
    int r = blockIdx.x * 256 + threadIdx.x;
    u32 m = 0x7f7fffffu;
#pragma unroll
    for (int o = 0; o < 64; ++o) m = min(m, partial[(size_t)o * N_BATCH + r]);
    negmin[r] = __uint_as_float(m);
}

// ---------------------------------------------------------------------------
// Kernel 4: val = d - neg_min[anchor] + margin; accumulate sum & count
// ---------------------------------------------------------------------------
__global__ __launch_bounds__(256) void k_pairs(const uint2* __restrict__ pairs,
                                               const float* __restrict__ negmin,
                                               const u32* __restrict__ totalsU,
                                               float* __restrict__ totalsF,
                                               u32 pairCap) {
    u32 n = totalsU[2]; if (n > pairCap) n = pairCap;
    float s = 0.f, c = 0.f;
    for (u32 k = blockIdx.x * 256u + threadIdx.x; k < n; k += gridDim.x * 256u) {
        uint2 p = pairs[k];
        float val = __uint_as_float(p.x) + MARGIN - negmin[p.y];
        if (val > 0.f) { s += val; c += 1.f; }
    }
#pragma unroll
    for (int off = 32; off > 0; off >>= 1) {
        s += __shfl_down(s, off, 64);
        c += __shfl_down(c, off, 64);
    }
    __shared__ float bs[4], bc[4];
    int lane = threadIdx.x & 63, w = threadIdx.x >> 6;
    if (lane == 0) { bs[w] = s; bc[w] = c; }
    __syncthreads();
    if (threadIdx.x == 0) {
        float S = bs[0] + bs[1] + bs[2] + bs[3];
        float Cc = bc[0] + bc[1] + bc[2] + bc[3];
        if (S != 0.f || Cc != 0.f) {
            atomicAdd(&totalsF[0], S);
            atomicAdd(&totalsF[1], Cc);
        }
    }
}

// ---------------------------------------------------------------------------
// Kernel 5: final scalar
// ---------------------------------------------------------------------------
__global__ void k_final(const float* __restrict__ totals, float* __restrict__ out) {
    out[0] = totals[0] / fmaxf(totals[1], 1.0f);
}

// ---------------------------------------------------------------------------
extern "C" void kernel_launch(void* const* d_in, const int* in_sizes, int n_in,
                              void* d_out, int out_size, void* d_ws, size_t ws_size,
                              hipStream_t stream) {
    const float* emb = (const float*)d_in[0];
    const int* labels = (const int*)d_in[1];

    // workspace carving (all offsets 256B-aligned)
    char* w = (char*)d_ws;
    const size_t ebf_bytes = (size_t)N_BATCH * EMB_DIM * sizeof(u16);   // 2 MB
    u16* ebf = (u16*)w;
    size_t off = ebf_bytes;
    float* sq = (float*)(w + off);       off += (size_t)N_BATCH * 4;    // 32 KB
    float* negmin = (float*)(w + off);   off += (size_t)N_BATCH * 4;    // 32 KB
    u32* totals = (u32*)(w + off);       off += 256;
    u32* partial = (u32*)(w + off);      off += (size_t)64 * N_BATCH * 4; // 2 MB
    uint2* pairs = (uint2*)(w + off);
    u32 pairCap = PAIR_CAP_MAX;
    if (ws_size > off) {
        size_t avail = (ws_size - off) / sizeof(uint2);
        if (avail < pairCap) pairCap = (u32)avail;
    } else {
        pairCap = 0;
    }

    k_prep<<<N_BATCH / 8, 256, 0, stream>>>(emb, ebf, sq, totals);
    k_gram<<<2080, 256, 0, stream>>>(ebf, sq, labels, partial, totals + 2, pairs, pairCap);
    k_negmin<<<N_BATCH / 256, 256, 0, stream>>>(partial, negmin);
    k_pairs<<<256, 256, 0, stream>>>(pairs, negmin, totals, (float*)totals, pairCap);
    k_final<<<1, 1, 0, stream>>>((const float*)totals, (float*)d_out);
}

// Round 3
// 118.998 us; speedup vs baseline: 1.2916x; 1.2814x over previous
//
#include <hip/hip_runtime.h>
#include <hip/hip_bf16.h>

typedef unsigned int u32;
typedef unsigned short u16;
typedef unsigned long long u64;

#define N_BATCH 8192
#define EMB_DIM 128
#define MARGIN 1.0f
#define CAP 256          // max members per class (mean 128, sd ~11 -> 11 sigma)
#define BIGF 3.3e38f

typedef __attribute__((ext_vector_type(8))) short bf16x8;   // 8 bf16 = 4 VGPRs
typedef __attribute__((ext_vector_type(4))) float f32x4;    // MFMA 16x16 acc

// async global->LDS, 16B per lane; lds dest is wave-uniform base (+lane*16 implicit)
__device__ inline void async_ld16(const void* g, void* l) {
    __builtin_amdgcn_global_load_lds(
        (const __attribute__((address_space(1))) unsigned int*)g,
        (__attribute__((address_space(3))) unsigned int*)l, 16, 0, 0);
}

// ---------------------------------------------------------------------------
// Kernel 1: bf16 cast + row sq-norms + init negmin/totals.
// 1024 blocks x 256 thr, 8 rows/block, 32 lanes/row, float4 loads.
// ---------------------------------------------------------------------------
__global__ __launch_bounds__(256) void k_prep(const float* __restrict__ emb,
                                              u16* __restrict__ ebf,
                                              float* __restrict__ sq,
                                              u32* __restrict__ negmin,
                                              u32* __restrict__ totals) {
    int t = threadIdx.x;
    int g = blockIdx.x * 256 + t;
    int r = blockIdx.x * 8 + (t >> 5);
    int l32 = t & 31;
    float4 x = ((const float4*)emb)[(size_t)r * 32 + l32];
    u32 ux = __float_as_uint(x.x), uy = __float_as_uint(x.y);
    u32 uz = __float_as_uint(x.z), uw = __float_as_uint(x.w);
    ushort4 b;
    b.x = (u16)((ux + 0x7fffu + ((ux >> 16) & 1u)) >> 16);
    b.y = (u16)((uy + 0x7fffu + ((uy >> 16) & 1u)) >> 16);
    b.z = (u16)((uz + 0x7fffu + ((uz >> 16) & 1u)) >> 16);
    b.w = (u16)((uw + 0x7fffu + ((uw >> 16) & 1u)) >> 16);
    ((ushort4*)ebf)[(size_t)r * 32 + l32] = b;

    float v = fmaf(x.x, x.x, fmaf(x.y, x.y, fmaf(x.z, x.z, x.w * x.w)));
    v += __shfl_down(v, 16, 64);   // 32-lane reduce; lanes 0 and 32 hold row sums
    v += __shfl_down(v, 8, 64);
    v += __shfl_down(v, 4, 64);
    v += __shfl_down(v, 2, 64);
    v += __shfl_down(v, 1, 64);
    if (l32 == 0) sq[r] = v;
    if (g < N_BATCH) negmin[g] = 0x7f7fffffu;   // FLT_MAX bits; dists clamped >=0 so uint order works
    if (g < 4) totals[g] = 0u;                  // sumF, cntF, (unused), ticket
}

// ---------------------------------------------------------------------------
// Kernel 2: fused Gram + masked row/col min -> global atomicMin(negmin).
// Triangular 1D grid (2080 blocks), 128x128 tile, B in 32KB LDS via
// global_load_lds (XOR swizzle folded into source addr), A from global.
// Each wave: 64 rows x 64 cols. NO pair machinery (k_class handles pairs).
// ---------------------------------------------------------------------------
__global__ __launch_bounds__(256, 4) void k_gram(const u16* __restrict__ ebf,
                                                 const float* __restrict__ sq,
                                                 const int* __restrict__ labels,
                                                 u32* __restrict__ negmin) {
    // ---- triangular decode: idx -> (bx, by), by >= bx
    int idx = blockIdx.x;
    float ff = (129.0f - sqrtf(16641.0f - 8.0f * (float)idx)) * 0.5f;
    int bx = (int)ff;
    if (bx > 63) bx = 63;
    while (bx > 0 && idx < bx * 64 - (bx * (bx - 1)) / 2) --bx;
    while (idx >= (bx + 1) * 64 - ((bx + 1) * bx) / 2) ++bx;
    int by = bx + idx - (bx * 64 - (bx * (bx - 1)) / 2);
    const int R = bx * 128, C = by * 128;
    const bool diag = (bx == by);

    __shared__ uint4 Bs[2048];   // 32 KB B tile; reused as rowmin/colmin in epilogue
    const int t = threadIdx.x;
    const int lane = t & 63, w = t >> 6;
    const int c16 = lane & 15, quad = lane >> 4;
    const uint4* gE = (const uint4*)ebf;

    // stage B tile (rows C..C+127) via async DMA, swizzle at the source
#pragma unroll
    for (int it = 0; it < 8; ++it) {
        int s = w * 512 + it * 64 + lane;
        int row = s >> 4, chPos = s & 15;
        int ch = chPos ^ (row & 15);
        async_ld16(gE + (size_t)(C + row) * 16 + ch, Bs + (w * 512 + it * 64));
    }

    const int mb = (w & 1) * 64;
    const int nb = (w >> 1) * 64;
    f32x4 acc[4][4];
#pragma unroll
    for (int i = 0; i < 4; ++i)
#pragma unroll
        for (int j = 0; j < 4; ++j) acc[i][j] = (f32x4){0.f, 0.f, 0.f, 0.f};

    const bf16x8* gA8 = (const bf16x8*)ebf;
    bf16x8 a[4];
#pragma unroll
    for (int i = 0; i < 4; ++i)
        a[i] = gA8[(size_t)(R + mb + i * 16 + c16) * 16 + quad];

    __syncthreads();   // drains LDS-DMA

    const bf16x8* Bs8 = (const bf16x8*)Bs;
#pragma unroll
    for (int kc = 0; kc < 4; ++kc) {
        int kch = kc * 4 + quad;
        bf16x8 b[4];
#pragma unroll
        for (int j = 0; j < 4; ++j) {
            int br = nb + j * 16 + c16;
            b[j] = Bs8[br * 16 + (kch ^ (br & 15))];
        }
        bf16x8 an[4];
        if (kc < 3) {
            int kn = (kc + 1) * 4 + quad;
#pragma unroll
            for (int i = 0; i < 4; ++i)
                an[i] = gA8[(size_t)(R + mb + i * 16 + c16) * 16 + kn];
        }
#pragma unroll
        for (int i = 0; i < 4; ++i)
#pragma unroll
            for (int j = 0; j < 4; ++j)
                acc[i][j] = __builtin_amdgcn_mfma_f32_16x16x32_bf16(a[i], b[j], acc[i][j], 0, 0, 0);
        if (kc < 3) {
#pragma unroll
            for (int i = 0; i < 4; ++i) a[i] = an[i];
        }
    }
    __syncthreads();   // B reads done; reuse LDS

    u32* rowmin = (u32*)Bs;         // [128]
    u32* colmin = rowmin + 128;     // [128]
    rowmin[t] = 0x7f7fffffu;        // t<256 inits both
    __syncthreads();

    float cs_[4]; int cl_[4];
#pragma unroll
    for (int j = 0; j < 4; ++j) {
        int gc = C + nb + j * 16 + c16;
        cs_[j] = sq[gc];
        cl_[j] = labels[gc];
    }
    float cm[4] = {BIGF, BIGF, BIGF, BIGF};

#pragma unroll
    for (int i = 0; i < 4; ++i) {
        const int rowbase = mb + i * 16 + quad * 4;
        float rs_[4]; int rl_[4];
#pragma unroll
        for (int rg = 0; rg < 4; ++rg) {
            int gr = R + rowbase + rg;
            rs_[rg] = sq[gr];
            rl_[rg] = labels[gr];
        }
        float rm[4] = {BIGF, BIGF, BIGF, BIGF};
#pragma unroll
        for (int j = 0; j < 4; ++j) {
#pragma unroll
            for (int rg = 0; rg < 4; ++rg) {
                // C/D layout (m89/m91): D[row=quad*4+rg][col=lane&15]
                float d = fmaf(-2.f, acc[i][j][rg], rs_[rg] + cs_[j]);
                bool same = (rl_[rg] == cl_[j]);
                float cand = same ? BIGF : fmaxf(d, 0.f);
                rm[rg] = fminf(rm[rg], cand);
                cm[j] = fminf(cm[j], cand);
            }
        }
#pragma unroll
        for (int rg = 0; rg < 4; ++rg) {
            float v = rm[rg];
            v = fminf(v, __shfl_xor(v, 1, 64));
            v = fminf(v, __shfl_xor(v, 2, 64));
            v = fminf(v, __shfl_xor(v, 4, 64));
            v = fminf(v, __shfl_xor(v, 8, 64));
            if (c16 == 0) atomicMin(&rowmin[rowbase + rg], __float_as_uint(v));
        }
    }
    if (!diag) {
#pragma unroll
        for (int j = 0; j < 4; ++j) {
            float v = cm[j];
            v = fminf(v, __shfl_xor(v, 16, 64));
            v = fminf(v, __shfl_xor(v, 32, 64));
            if (quad == 0) atomicMin(&colmin[nb + j * 16 + c16], __float_as_uint(v));
        }
    }
    __syncthreads();

    if (t < 128) atomicMin(&negmin[R + t], rowmin[t]);
    else if (!diag) atomicMin(&negmin[C + t - 128], colmin[t - 128]);
}

// ---------------------------------------------------------------------------
// Kernel 3: per-class pair losses. One block per class: scan labels, gather
// member rows (bf16) into LDS, mini-MFMA Gram, val = d - negmin[anchor] + m,
// block reduce -> atomicAdd; last block (ticket) writes the final scalar.
// ---------------------------------------------------------------------------
__global__ __launch_bounds__(256) void k_class(const u16* __restrict__ ebf,
                                               const float* __restrict__ sq,
                                               const int* __restrict__ labels,
                                               const float* __restrict__ negmin,
                                               float* __restrict__ totalsF,
                                               u32* __restrict__ totalsU,
                                               float* __restrict__ out) {
    const int c = blockIdx.x;
    __shared__ uint4 Es[4096];      // 64 KB: up to 256 member rows, XOR-swizzled
    __shared__ u32 lmem[CAP];
    __shared__ float lnm[CAP], lsq[CAP];
    __shared__ u32 lcount;
    __shared__ float redS[4], redC[4];

    const int t = threadIdx.x;
    const int lane = t & 63, w = t >> 6;
    const int c16 = lane & 15, quad = lane >> 4;

    if (t == 0) lcount = 0;
    __syncthreads();
    for (int r = t; r < N_BATCH; r += 256)
        if (labels[r] == c) {
            u32 p = atomicAdd(&lcount, 1u);
            if (p < CAP) lmem[p] = (u32)r;
        }
    __syncthreads();
    int n = lcount; if (n > CAP) n = CAP;

    const uint4* gE = (const uint4*)ebf;
#pragma unroll
    for (int it = 0; it < 16; ++it) {
        int s = t + it * 256;
        int row = s >> 4, ch = s & 15;
        u32 m = (row < n) ? lmem[row] : 0u;     // clamp: no OOB reads for pad rows
        Es[row * 16 + (ch ^ (row & 15))] = gE[(size_t)m * 16 + ch];
    }
    if (t < n) { lnm[t] = negmin[lmem[t]]; lsq[t] = sq[lmem[t]]; }
    __syncthreads();

    const bf16x8* Es8 = (const bf16x8*)Es;
    float ssum = 0.f, scnt = 0.f;

    for (int cp = 0; cp < 4; ++cp) {   // col panels of 64; wave w owns rows w*64..+63
        f32x4 acc[4][4];
#pragma unroll
        for (int i = 0; i < 4; ++i)
#pragma unroll
            for (int j = 0; j < 4; ++j) acc[i][j] = (f32x4){0.f, 0.f, 0.f, 0.f};
#pragma unroll
        for (int kc = 0; kc < 4; ++kc) {
            int kch = kc * 4 + quad;
            bf16x8 a[4], b[4];
#pragma unroll
            for (int i = 0; i < 4; ++i) {
                int ar = w * 64 + i * 16 + c16;
                a[i] = Es8[ar * 16 + (kch ^ (ar & 15))];
            }
#pragma unroll
            for (int j = 0; j < 4; ++j) {
                int br = cp * 64 + j * 16 + c16;
                b[j] = Es8[br * 16 + (kch ^ (br & 15))];
            }
#pragma unroll
            for (int i = 0; i < 4; ++i)
#pragma unroll
                for (int j = 0; j < 4; ++j)
                    acc[i][j] = __builtin_amdgcn_mfma_f32_16x16x32_bf16(a[i], b[j], acc[i][j], 0, 0, 0);
        }
        // epilogue for this 64x64 sub-tile
        float lsqq[4]; u32 oq[4]; bool qv[4];
#pragma unroll
        for (int j = 0; j < 4; ++j) {
            int q = cp * 64 + j * 16 + c16;
            qv[j] = (q < n);
            lsqq[j] = qv[j] ? lsq[q] : 0.f;
            oq[j] = qv[j] ? lmem[q] : 0u;       // 0 sentinel: opp<0 never true
        }
#pragma unroll
        for (int i = 0; i < 4; ++i) {
            int pb = w * 64 + i * 16 + quad * 4;
            float rcst[4]; u32 opp[4];
#pragma unroll
            for (int rg = 0; rg < 4; ++rg) {
                int p = pb + rg;
                bool pv = (p < n);
                rcst[rg] = pv ? (lsq[p] - lnm[p] + MARGIN) : -BIGF;
                opp[rg] = pv ? lmem[p] : 0xffffffffu;  // max sentinel: opp<oq never true
            }
#pragma unroll
            for (int j = 0; j < 4; ++j)
#pragma unroll
                for (int rg = 0; rg < 4; ++rg) {
                    float val = fmaf(-2.f, acc[i][j][rg], rcst[rg] + lsqq[j]);
                    bool ok = qv[j] && (opp[rg] < oq[j]) && (val > 0.f);
                    if (ok) { ssum += val; scnt += 1.f; }
                }
        }
    }

#pragma unroll
    for (int off = 32; off > 0; off >>= 1) {
        ssum += __shfl_down(ssum, off, 64);
        scnt += __shfl_down(scnt, off, 64);
    }
    if (lane == 0) { redS[w] = ssum; redC[w] = scnt; }
    __syncthreads();
    if (t == 0) {
        float S = redS[0] + redS[1] + redS[2] + redS[3];
        float Cc = redC[0] + redC[1] + redC[2] + redC[3];
        atomicAdd(&totalsF[0], S);
        atomicAdd(&totalsF[1], Cc);
        __threadfence();
        u32 tk = atomicAdd(&totalsU[3], 1u);
        if (tk == 63u) {                 // last class block: finalize
            __threadfence();
            float fs = atomicAdd(&totalsF[0], 0.f);
            float fc = atomicAdd(&totalsF[1], 0.f);
            out[0] = fs / fmaxf(fc, 1.0f);
        }
    }
}

// ---------------------------------------------------------------------------
extern "C" void kernel_launch(void* const* d_in, const int* in_sizes, int n_in,
                              void* d_out, int out_size, void* d_ws, size_t ws_size,
                              hipStream_t stream) {
    const float* emb = (const float*)d_in[0];
    const int* labels = (const int*)d_in[1];

    char* w = (char*)d_ws;
    const size_t ebf_bytes = (size_t)N_BATCH * EMB_DIM * sizeof(u16);   // 2 MB
    u16* ebf = (u16*)w;
    size_t off = ebf_bytes;
    float* sq = (float*)(w + off);     off += (size_t)N_BATCH * 4;      // 32 KB
    u32* negmin = (u32*)(w + off);     off += (size_t)N_BATCH * 4;      // 32 KB
    u32* totals = (u32*)(w + off);     off += 256;

    k_prep<<<N_BATCH / 8, 256, 0, stream>>>(emb, ebf, sq, negmin, totals);
    k_gram<<<2080, 256, 0, stream>>>(ebf, sq, labels, negmin);
    k_class<<<64, 256, 0, stream>>>(ebf, sq, labels, (const float*)negmin,
                                    (float*)totals, totals, (float*)d_out);
}